// Round 1
// baseline (413.165 us; speedup 1.0000x reference)
//
#include <hip/hip_runtime.h>

#define NPOS 4096
#define SCALE_QK 0.17677669529663687f   // 1/sqrt(32)

__device__ __forceinline__ unsigned pack_bf16x2(float a, float b) {
    unsigned ua = __float_as_uint(a);
    unsigned ub = __float_as_uint(b);
    ua = (ua + 0x7fffu + ((ua >> 16) & 1u)) >> 16;          // RNE to bf16, low half
    ub = (ub + 0x7fffu + ((ub >> 16) & 1u)) & 0xffff0000u;  // RNE to bf16, high half
    return ua | ub;
}

// Y[b][o][p] = epilogue( sum_c W[o][c] * (X1[b][c][p] + X2[b][c][p]) )
// epilogue: y = y*sc[o] + bi[o]; optional silu; optional += addout[b][o][p]
__global__ __launch_bounds__(256) void gemm_bias_kernel(
    const float* __restrict__ X1, const float* __restrict__ X2,
    const float* __restrict__ W, const float* __restrict__ sc,
    const float* __restrict__ bi, const float* __restrict__ addout,
    float* __restrict__ Y, int M, int K, int do_silu)
{
    __shared__ float Ws[32][68];   // [k][o], stride 68 keeps float4 16B-aligned
    __shared__ float Xs[32][64];   // [k][p]
    const int tid = threadIdx.x;
    const int tx = tid & 15, ty = tid >> 4;
    const int pBase = blockIdx.x * 64;
    const int oBase = blockIdx.y * 64;
    const int b = blockIdx.z;
    const float* Xb1 = X1 + (size_t)b * K * NPOS;
    const float* Xb2 = X2 ? X2 + (size_t)b * K * NPOS : nullptr;
    float acc[4][4] = {};
    const bool wvec = ((K & 3) == 0);   // w_m2 rows (K=307) are not 16B aligned

    for (int k0 = 0; k0 < K; k0 += 32) {
        // W tile: 64 o x 32 c, transpose-on-store
        #pragma unroll
        for (int i = 0; i < 2; i++) {
            int f4 = tid * 2 + i;          // 0..511
            int oo = f4 >> 3;              // 8 float4 per row of 32
            int cv = (f4 & 7) * 4;
            int o = oBase + oo;
            float w0 = 0.f, w1 = 0.f, w2 = 0.f, w3 = 0.f;
            if (o < M) {
                if (wvec && (k0 + 32 <= K)) {
                    float4 w4 = *(const float4*)&W[(size_t)o * K + k0 + cv];
                    w0 = w4.x; w1 = w4.y; w2 = w4.z; w3 = w4.w;
                } else {
                    int cb = k0 + cv;
                    if (cb + 0 < K) w0 = W[(size_t)o * K + cb + 0];
                    if (cb + 1 < K) w1 = W[(size_t)o * K + cb + 1];
                    if (cb + 2 < K) w2 = W[(size_t)o * K + cb + 2];
                    if (cb + 3 < K) w3 = W[(size_t)o * K + cb + 3];
                }
            }
            Ws[cv + 0][oo] = w0;
            Ws[cv + 1][oo] = w1;
            Ws[cv + 2][oo] = w2;
            Ws[cv + 3][oo] = w3;
        }
        // X tile: 32 c x 64 p
        #pragma unroll
        for (int i = 0; i < 2; i++) {
            int f4 = tid * 2 + i;
            int kk = f4 >> 4;
            int pv = (f4 & 15) * 4;
            int c = k0 + kk;
            float4 x4 = make_float4(0.f, 0.f, 0.f, 0.f);
            if (c < K) {
                x4 = *(const float4*)&Xb1[(size_t)c * NPOS + pBase + pv];
                if (Xb2) {
                    float4 e4 = *(const float4*)&Xb2[(size_t)c * NPOS + pBase + pv];
                    x4.x += e4.x; x4.y += e4.y; x4.z += e4.z; x4.w += e4.w;
                }
            }
            *(float4*)&Xs[kk][pv] = x4;
        }
        __syncthreads();
        #pragma unroll
        for (int kk = 0; kk < 32; kk++) {
            float4 a4 = *(const float4*)&Ws[kk][ty * 4];
            float4 b4 = *(const float4*)&Xs[kk][tx * 4];
            float as[4] = {a4.x, a4.y, a4.z, a4.w};
            float bs[4] = {b4.x, b4.y, b4.z, b4.w};
            #pragma unroll
            for (int r = 0; r < 4; r++)
                #pragma unroll
                for (int cc = 0; cc < 4; cc++)
                    acc[r][cc] = fmaf(as[r], bs[cc], acc[r][cc]);
        }
        __syncthreads();
    }
    #pragma unroll
    for (int r = 0; r < 4; r++) {
        int o = oBase + ty * 4 + r;
        if (o < M) {
            float s = sc[o], bv = bi[o];
            size_t idx = ((size_t)b * M + o) * NPOS + pBase + tx * 4;
            float4 y;
            y.x = acc[r][0] * s + bv;
            y.y = acc[r][1] * s + bv;
            y.z = acc[r][2] * s + bv;
            y.w = acc[r][3] * s + bv;
            if (do_silu) {
                y.x = y.x / (1.f + __expf(-y.x));
                y.y = y.y / (1.f + __expf(-y.y));
                y.z = y.z / (1.f + __expf(-y.z));
                y.w = y.w / (1.f + __expf(-y.w));
            }
            if (addout) {
                float4 a4 = *(const float4*)&addout[idx];
                y.x += a4.x; y.y += a4.y; y.z += a4.z; y.w += a4.w;
            }
            *(float4*)&Y[idx] = y;
        }
    }
}

// depthwise 3x3, zero pad, per-channel scale/bias
__global__ __launch_bounds__(256) void dwconv3_kernel(
    const float* __restrict__ v4, const float* __restrict__ wpe,
    const float* __restrict__ spe, const float* __restrict__ bpe,
    float* __restrict__ pe)
{
    int idx = blockIdx.x * 256 + threadIdx.x;   // over 2*256*4096
    int p = idx & 4095;
    int bc = idx >> 12;
    int c = bc & 255;
    int h = p >> 6, w = p & 63;
    const float* src = v4 + (size_t)bc * 4096;
    float acc = 0.f;
    #pragma unroll
    for (int di = 0; di < 3; di++) {
        int hh = h + di - 1;
        if (hh < 0 || hh > 63) continue;
        #pragma unroll
        for (int dj = 0; dj < 3; dj++) {
            int ww = w + dj - 1;
            if (ww < 0 || ww > 63) continue;
            acc += src[hh * 64 + ww] * wpe[c * 9 + di * 3 + dj];
        }
    }
    pe[idx] = acc * spe[c] + bpe[c];
}

// Area attention. Area reshape index map (derived from row-major reshape):
//  q[4b+g, h, d, na] = qk[b][g*128 +      h*8 + (d>>2)][(d&3)*1024 + na]
//  k[4b+g, h, d, na] = qk[b][g*128 + 64 + h*8 + (d>>2)][(d&3)*1024 + na]
//  v[4b+g, h, d, na] = v4[b][g*64  +      h*8 + (d>>2)][(d&3)*1024 + na]
//  out written with the inverse of the v map.
// Block: (ntile, h, ba). 128 queries/block, flash-style over 16 chunks of 64 keys.
__global__ __launch_bounds__(256) void area_attn_kernel(
    const float* __restrict__ qk, const float* __restrict__ v4,
    float* __restrict__ att)
{
    __shared__ float Qs[32][128];        // [d][n]  (reused as O staging at end)
    __shared__ float Ks[32][64];         // [d][m]
    __shared__ float Vt[64][34];         // [m][d], pad->34 keeps float2 aligned + conflict-light
    __shared__ unsigned PTu[64][68];     // P^T as bf16x2: [m][n/2], row stride 68 words
    const int tid = threadIdx.x;
    const int tn = tid >> 4;             // 0..15 : row group (8 n each)
    const int tm = tid & 15;             // 0..15 : S: 4 m each; PV: 2 d each
    const int ntile = blockIdx.x;
    const int h = blockIdx.y;
    const int ba = blockIdx.z;
    const int b = ba >> 2, g = ba & 3;
    const int n0 = ntile * 128;

    // load Q tile (pre-scaled)
    #pragma unroll
    for (int pass = 0; pass < 4; pass++) {
        int d = pass * 8 + (tid >> 5);
        int nv = (tid & 31) * 4;
        int o = g * 128 + h * 8 + (d >> 2);
        const float* qrow = qk + ((size_t)(b * 512 + o)) * NPOS + (d & 3) * 1024 + n0;
        float4 q4 = *(const float4*)&qrow[nv];
        Qs[d][nv + 0] = q4.x * SCALE_QK;
        Qs[d][nv + 1] = q4.y * SCALE_QK;
        Qs[d][nv + 2] = q4.z * SCALE_QK;
        Qs[d][nv + 3] = q4.w * SCALE_QK;
    }

    float oacc[8][2] = {};
    float Mrow[8], Lrow[8];
    #pragma unroll
    for (int i = 0; i < 8; i++) { Mrow[i] = -3.0e38f; Lrow[i] = 0.f; }

    for (int m0 = 0; m0 < 1024; m0 += 64) {
        __syncthreads();   // protect Ks/Vt/PTu against previous chunk's readers
        // K chunk
        #pragma unroll
        for (int i = 0; i < 2; i++) {
            int f4 = tid * 2 + i;          // 0..511
            int d = f4 >> 4;
            int mv = (f4 & 15) * 4;
            int o = g * 128 + 64 + h * 8 + (d >> 2);
            const float* krow = qk + ((size_t)(b * 512 + o)) * NPOS + (d & 3) * 1024 + m0;
            *(float4*)&Ks[d][mv] = *(const float4*)&krow[mv];
        }
        // V chunk, transposed into Vt[m][d]
        {
            int m = tid & 63;
            int db = tid >> 6;
            #pragma unroll
            for (int i = 0; i < 8; i++) {
                int d = i * 4 + db;
                int c = g * 64 + h * 8 + (d >> 2);
                const float* vrow = v4 + ((size_t)(b * 256 + c)) * NPOS + (d & 3) * 1024 + m0;
                Vt[m][d] = vrow[m];
            }
        }
        __syncthreads();
        // S = (scaled q)^T k : 8n x 4m per thread
        float sp[8][4] = {};
        #pragma unroll 8
        for (int d = 0; d < 32; d++) {
            float4 qa = *(const float4*)&Qs[d][tn * 8];
            float4 qb = *(const float4*)&Qs[d][tn * 8 + 4];
            float4 kv = *(const float4*)&Ks[d][tm * 4];
            float qs[8] = {qa.x, qa.y, qa.z, qa.w, qb.x, qb.y, qb.z, qb.w};
            float ks[4] = {kv.x, kv.y, kv.z, kv.w};
            #pragma unroll
            for (int i = 0; i < 8; i++)
                #pragma unroll
                for (int j = 0; j < 4; j++)
                    sp[i][j] = fmaf(qs[i], ks[j], sp[i][j]);
        }
        // online softmax; row stats reduced over the 16 tm lanes (lane bits 0..3)
        #pragma unroll
        for (int i = 0; i < 8; i++) {
            float mx = fmaxf(fmaxf(sp[i][0], sp[i][1]), fmaxf(sp[i][2], sp[i][3]));
            #pragma unroll
            for (int wsh = 1; wsh < 16; wsh <<= 1)
                mx = fmaxf(mx, __shfl_xor(mx, wsh, 64));
            float Mn = fmaxf(Mrow[i], mx);
            float al = __expf(Mrow[i] - Mn);
            float sum = 0.f;
            #pragma unroll
            for (int j = 0; j < 4; j++) { sp[i][j] = __expf(sp[i][j] - Mn); sum += sp[i][j]; }
            #pragma unroll
            for (int wsh = 1; wsh < 16; wsh <<= 1)
                sum += __shfl_xor(sum, wsh, 64);
            Lrow[i] = Lrow[i] * al + sum;
            Mrow[i] = Mn;
            oacc[i][0] *= al;
            oacc[i][1] *= al;
        }
        // write P^T (bf16 pairs): PTu[m][n/2]
        #pragma unroll
        for (int j = 0; j < 4; j++) {
            int m = tm * 4 + j;
            uint4 pk;
            pk.x = pack_bf16x2(sp[0][j], sp[1][j]);
            pk.y = pack_bf16x2(sp[2][j], sp[3][j]);
            pk.z = pack_bf16x2(sp[4][j], sp[5][j]);
            pk.w = pack_bf16x2(sp[6][j], sp[7][j]);
            *(uint4*)&PTu[m][tn * 4] = pk;
        }
        __syncthreads();
        // PV: O[n = tn*8+i][d = tm*2+{0,1}] += P[n,m] * V[d,m]
        #pragma unroll 8
        for (int m = 0; m < 64; m++) {
            uint4 pu = *(const uint4*)&PTu[m][tn * 4];
            float2 vv = *(const float2*)&Vt[m][tm * 2];
            float pvv[8];
            pvv[0] = __uint_as_float(pu.x << 16);
            pvv[1] = __uint_as_float(pu.x & 0xffff0000u);
            pvv[2] = __uint_as_float(pu.y << 16);
            pvv[3] = __uint_as_float(pu.y & 0xffff0000u);
            pvv[4] = __uint_as_float(pu.z << 16);
            pvv[5] = __uint_as_float(pu.z & 0xffff0000u);
            pvv[6] = __uint_as_float(pu.w << 16);
            pvv[7] = __uint_as_float(pu.w & 0xffff0000u);
            #pragma unroll
            for (int i = 0; i < 8; i++) {
                oacc[i][0] = fmaf(pvv[i], vv.x, oacc[i][0]);
                oacc[i][1] = fmaf(pvv[i], vv.y, oacc[i][1]);
            }
        }
    }
    __syncthreads();
    // stage normalized O into Qs[d][n], then coalesced global write
    #pragma unroll
    for (int i = 0; i < 8; i++) {
        float inv = 1.f / Lrow[i];
        Qs[tm * 2 + 0][tn * 8 + i] = oacc[i][0] * inv;
        Qs[tm * 2 + 1][tn * 8 + i] = oacc[i][1] * inv;
    }
    __syncthreads();
    #pragma unroll
    for (int pass = 0; pass < 4; pass++) {
        int f4i = pass * 256 + tid;
        int d = f4i >> 5;
        int nv = (f4i & 31) * 4;
        int c = g * 64 + h * 8 + (d >> 2);
        float* orow = att + ((size_t)(b * 256 + c)) * NPOS + (d & 3) * 1024 + n0;
        *(float4*)&orow[nv] = *(const float4*)&Qs[d][nv];
    }
}

extern "C" void kernel_launch(void* const* d_in, const int* in_sizes, int n_in,
                              void* d_out, int out_size, void* d_ws, size_t ws_size,
                              hipStream_t stream)
{
    const float* x      = (const float*)d_in[0];
    const float* w_qk   = (const float*)d_in[1];
    const float* s_qk   = (const float*)d_in[2];
    const float* b_qk   = (const float*)d_in[3];
    const float* w_v    = (const float*)d_in[4];
    const float* s_v    = (const float*)d_in[5];
    const float* b_v    = (const float*)d_in[6];
    const float* w_pe   = (const float*)d_in[7];
    const float* s_pe   = (const float*)d_in[8];
    const float* b_pe   = (const float*)d_in[9];
    const float* w_proj = (const float*)d_in[10];
    const float* s_proj = (const float*)d_in[11];
    const float* b_proj = (const float*)d_in[12];
    const float* w_m1   = (const float*)d_in[13];
    const float* s_m1   = (const float*)d_in[14];
    const float* b_m1   = (const float*)d_in[15];
    const float* w_m2   = (const float*)d_in[16];
    const float* s_m2   = (const float*)d_in[17];
    const float* b_m2   = (const float*)d_in[18];
    float* out = (float*)d_out;
    const int MLP = in_sizes[13] / 256;   // 307

    float* ws     = (float*)d_ws;
    float* qk_ws  = ws;                              // 2*512*4096
    float* v4_ws  = qk_ws + 2 * 512 * NPOS;          // 2*256*4096
    float* pe_ws  = v4_ws + 2 * 256 * NPOS;
    float* att_ws = pe_ws + 2 * 256 * NPOS;
    float* x1_ws  = att_ws + 2 * 256 * NPOS;
    float* mh_ws  = x1_ws + 2 * 256 * NPOS;          // 2*MLP*4096

    dim3 blk(256);
    // qk = conv1x1(x, w_qk)
    gemm_bias_kernel<<<dim3(64, 8, 2), blk, 0, stream>>>(
        x, nullptr, w_qk, s_qk, b_qk, nullptr, qk_ws, 512, 256, 0);
    // v4 = conv1x1(x, w_v)
    gemm_bias_kernel<<<dim3(64, 4, 2), blk, 0, stream>>>(
        x, nullptr, w_v, s_v, b_v, nullptr, v4_ws, 256, 256, 0);
    // pe = dwconv3x3(v4)
    dwconv3_kernel<<<dim3(2 * 256 * NPOS / 256), blk, 0, stream>>>(
        v4_ws, w_pe, s_pe, b_pe, pe_ws);
    // area attention
    area_attn_kernel<<<dim3(8, 8, 8), blk, 0, stream>>>(qk_ws, v4_ws, att_ws);
    // x1 = x + conv1x1(att + pe, w_proj)
    gemm_bias_kernel<<<dim3(64, 4, 2), blk, 0, stream>>>(
        att_ws, pe_ws, w_proj, s_proj, b_proj, x, x1_ws, 256, 256, 0);
    // mh = silu(conv1x1(x1, w_m1))
    gemm_bias_kernel<<<dim3(64, (MLP + 63) / 64, 2), blk, 0, stream>>>(
        x1_ws, nullptr, w_m1, s_m1, b_m1, nullptr, mh_ws, MLP, 256, 1);
    // out = x1 + conv1x1(mh, w_m2)
    gemm_bias_kernel<<<dim3(64, 4, 2), blk, 0, stream>>>(
        mh_ws, nullptr, w_m2, s_m2, b_m2, x1_ws, out, 256, MLP, 0);
}